// Round 1
// baseline (1339.879 us; speedup 1.0000x reference)
//
#include <hip/hip_runtime.h>
#include <cstdint>

#define TEMP_C 20.0f

typedef float f32x4 __attribute__((ext_vector_type(4)));
typedef __bf16 bf16x8 __attribute__((ext_vector_type(8)));

// fp32 -> bf16 round-to-nearest-even
__device__ __forceinline__ unsigned short f2bf(float f) {
  union { float f; unsigned int u; } v; v.f = f;
  unsigned int r = v.u + 0x7FFFu + ((v.u >> 16) & 1u);
  return (unsigned short)(r >> 16);
}

// async global->LDS, 16B per lane (dest must be wave-uniform base + lane*16)
__device__ __forceinline__ void gload_lds16(const void* g, void* l) {
#if defined(__has_builtin) && __has_builtin(__builtin_amdgcn_global_load_lds)
  __builtin_amdgcn_global_load_lds(
      (__attribute__((address_space(1))) void*)(g),
      (__attribute__((address_space(3))) void*)(l), 16, 0, 0);
#else
  *(uint4*)l = *(const uint4*)g;
#endif
}

// ---------------------------------------------------------------------------
// 1) per-pixel inverse L2 norm over channels: invn[p] = 1/max(||X[:,p]||, 1e-12)
//    X is (C, 3600) fp32. 256 threads = 64 pixels x 4 channel-slices. Deterministic.
__global__ __launch_bounds__(256) void colnorm_inv_k(
    const float* __restrict__ X, float* __restrict__ invn, int C)
{
  __shared__ float red[4][64];
  const int pix = threadIdx.x & 63;
  const int sub = threadIdx.x >> 6;
  const int p = blockIdx.x * 64 + pix;
  float s = 0.f;
  if (p < 3600) {
    for (int c = sub; c < C; c += 4) {
      float v = X[(size_t)c * 3600 + p];
      s += v * v;
    }
  }
  red[sub][pix] = s;
  __syncthreads();
  if (sub == 0 && p < 3600) {
    float t = red[0][pix] + red[1][pix] + red[2][pix] + red[3][pix];
    invn[p] = 1.0f / fmaxf(sqrtf(t), 1e-12f);
  }
}

// ---------------------------------------------------------------------------
// 2) transpose + scale + bf16 cast: T[p][cdst0+c] = bf16(X[c][p] * invn[p] * mult)
//    T has row stride 3072 (K-contiguous for the GEMM). mult = TEMP*w_chan[widx] or 1.
__global__ __launch_bounds__(256) void tpose_k(
    const float* __restrict__ X, const float* __restrict__ invn,
    const float* __restrict__ wch, int widx,
    unsigned short* __restrict__ T, int cdst0)
{
  __shared__ float tile[32][33];
  const int tx = threadIdx.x, ty = threadIdx.y;
  const int p0 = blockIdx.x * 32, c0 = blockIdx.y * 32;
  const float mult = (widx >= 0) ? TEMP_C * wch[widx] : 1.0f;
  #pragma unroll
  for (int i = 0; i < 4; ++i) {
    int c = c0 + ty + i * 8, p = p0 + tx;
    tile[ty + i * 8][tx] = (p < 3600) ? X[(size_t)c * 3600 + p] : 0.f;
  }
  __syncthreads();
  #pragma unroll
  for (int i = 0; i < 4; ++i) {
    int p = p0 + ty + i * 8;
    if (p < 3600) {
      float sc = invn[p] * mult;
      T[(size_t)p * 3072 + cdst0 + c0 + tx] = f2bf(tile[tx][ty + i * 8] * sc);
    }
  }
}

// ---------------------------------------------------------------------------
// 3) V cast: f_s (512, 3600) fp32 -> V (512, 3712) bf16 (pad pre-zeroed)
__global__ void castv_k(const float* __restrict__ X, unsigned short* __restrict__ V)
{
  int i = blockIdx.x * 256 + threadIdx.x;
  if (i >= 512 * 3600) return;
  int c = i / 3600, s = i - c * 3600;
  V[(size_t)c * 3712 + s] = f2bf(X[i]);
}

// ---------------------------------------------------------------------------
// 4) GEMM: C[m][n] (+)= sum_k A[m][k]*B[n][k], bf16 in / fp32 out.
//    128x128 tile, BK=32, 4 waves (2x2 of 64x64), mfma_f32_16x16x32_bf16.
//    M,N must be multiples of 128; K multiple of 32. Single-buffered LDS,
//    global_load_lds staging (m97 structure).
__global__ __launch_bounds__(256) void gemm_bt_k(
    const unsigned short* __restrict__ A, const unsigned short* __restrict__ B,
    float* __restrict__ C, int K, int lda, int ldb, int ldc, int accumulate)
{
  __shared__ __align__(16) unsigned short As[128 * 32];
  __shared__ __align__(16) unsigned short Bs[128 * 32];
  const int tid = threadIdx.x;
  const int lane = tid & 63;
  const int wave = tid >> 6;
  const int wm = (wave >> 1) * 64;   // wave's 64x64 quadrant
  const int wn = (wave & 1) * 64;
  const long Arow0 = (long)blockIdx.x * 128;
  const long Brow0 = (long)blockIdx.y * 128;

  f32x4 acc[4][4] = {};

  const int r  = lane & 15;          // fragment row/col within 16
  const int kb = (lane >> 4) * 8;    // fragment k-base (8 contiguous bf16)

  for (int k0 = 0; k0 < K; k0 += 32) {
    // stage A(128x32) and B(128x32): 8 chunks of 1KB each, 2 passes x 4 waves
    #pragma unroll
    for (int pass = 0; pass < 2; ++pass) {
      const int chunk = pass * 4 + wave;
      const int m  = chunk * 16 + (lane >> 2);
      const int ke = (lane & 3) * 8;
      gload_lds16(A + (Arow0 + m) * (long)lda + k0 + ke, &As[chunk * 512 + lane * 8]);
      gload_lds16(B + (Brow0 + m) * (long)ldb + k0 + ke, &Bs[chunk * 512 + lane * 8]);
    }
    __syncthreads();  // compiler drains vmcnt(0) here

    bf16x8 af[4], bfr[4];
    #pragma unroll
    for (int f = 0; f < 4; ++f) {
      af[f]  = *(const bf16x8*)&As[(wm + f * 16 + r) * 32 + kb];
      bfr[f] = *(const bf16x8*)&Bs[(wn + f * 16 + r) * 32 + kb];
    }
    #pragma unroll
    for (int i = 0; i < 4; ++i)
      #pragma unroll
      for (int j = 0; j < 4; ++j)
        acc[i][j] = __builtin_amdgcn_mfma_f32_16x16x32_bf16(af[i], bfr[j], acc[i][j], 0, 0, 0);
    __syncthreads();
  }

  // epilogue: D row = (lane>>4)*4 + reg, col = lane&15  [verified C/D layout]
  const int rb = (lane >> 4) * 4;
  const int cn = lane & 15;
  #pragma unroll
  for (int i = 0; i < 4; ++i) {
    #pragma unroll
    for (int ii = 0; ii < 4; ++ii) {
      long m = Arow0 + wm + i * 16 + rb + ii;
      float* cp = C + m * (long)ldc + Brow0 + wn + cn;
      #pragma unroll
      for (int j = 0; j < 4; ++j) {
        float v = acc[i][j][ii];
        if (accumulate) cp[j * 16] += v; else cp[j * 16] = v;
      }
    }
  }
}

// ---------------------------------------------------------------------------
// 5) row softmax over s<3600, written IN-PLACE as bf16 into the fp32 row
//    (row byte stride 3712*4; bf16 row occupies first 7424 bytes -> lda=7424).
//    Also zeroes bf16 pad s in [3600,3712).
__global__ __launch_bounds__(256) void softmax_rows_k(float* __restrict__ logits)
{
  const int q = blockIdx.x;
  float* row = logits + (size_t)q * 3712;
  unsigned short* orow = (unsigned short*)row;
  const int tid = threadIdx.x;
  float v[15];
  float mx = -1e30f;
  #pragma unroll
  for (int j = 0; j < 15; ++j) {
    int s = tid + j * 256;
    float x = (s < 3600) ? row[s] : -1e30f;
    v[j] = x;
    mx = fmaxf(mx, x);
  }
  #pragma unroll
  for (int o = 32; o > 0; o >>= 1) mx = fmaxf(mx, __shfl_xor(mx, o));
  __shared__ float wmax[4], wsum[4];
  if ((tid & 63) == 0) wmax[tid >> 6] = mx;
  __syncthreads();
  mx = fmaxf(fmaxf(wmax[0], wmax[1]), fmaxf(wmax[2], wmax[3]));
  float sum = 0.f;
  #pragma unroll
  for (int j = 0; j < 15; ++j) {
    int s = tid + j * 256;
    float e = (s < 3600) ? __expf(v[j] - mx) : 0.f;
    v[j] = e;
    sum += e;
  }
  #pragma unroll
  for (int o = 32; o > 0; o >>= 1) sum += __shfl_xor(sum, o);
  if ((tid & 63) == 0) wsum[tid >> 6] = sum;
  __syncthreads();  // also orders: all row reads above happen before writes below
  sum = wsum[0] + wsum[1] + wsum[2] + wsum[3];
  const float inv = 1.0f / sum;
  #pragma unroll
  for (int j = 0; j < 15; ++j) {
    int s = tid + j * 256;
    if (s < 3600) orow[s] = f2bf(v[j] * inv);
    else if (s < 3712) orow[s] = 0;
  }
}

// ---------------------------------------------------------------------------
// 6) out[c][p] = 0.5*f_q[c][p] + 0.25*P[p][c]   (P = att0+att1, mean/2 * ATT_WT)
__global__ __launch_bounds__(256) void final_blend_k(
    const float* __restrict__ P, const float* __restrict__ fq, float* __restrict__ out)
{
  __shared__ float t[32][33];
  const int tx = threadIdx.x, ty = threadIdx.y;
  const int p0 = blockIdx.x * 32, c0 = blockIdx.y * 32;
  #pragma unroll
  for (int i = 0; i < 4; ++i) {
    int p = p0 + ty + i * 8, c = c0 + tx;
    t[ty + i * 8][tx] = (p < 3600) ? P[(size_t)p * 512 + c] : 0.f;
  }
  __syncthreads();
  #pragma unroll
  for (int i = 0; i < 4; ++i) {
    int c = c0 + ty + i * 8, p = p0 + tx;
    if (p < 3600) {
      size_t o = (size_t)c * 3600 + p;
      out[o] = 0.5f * fq[o] + 0.25f * t[tx][ty + i * 8];
    }
  }
}

// ---------------------------------------------------------------------------
extern "C" void kernel_launch(void* const* d_in, const int* in_sizes, int n_in,
                              void* d_out, int out_size, void* d_ws, size_t ws_size,
                              hipStream_t stream) {
  const float* fq3 = (const float*)d_in[0];  // (1,1024,60,60)
  const float* fq4 = (const float*)d_in[1];  // (1,2048,60,60)
  const float* fs3 = (const float*)d_in[2];  // (2,1024,60,60)
  const float* fs4 = (const float*)d_in[3];  // (2,2048,60,60)
  const float* f_q = (const float*)d_in[4];  // (1,512,60,60)
  const float* f_s = (const float*)d_in[5];  // (2,512,60,60)
  const float* wch = (const float*)d_in[6];  // (2,)
  float* out = (float*)d_out;

  const size_t HW = 3600, MP = 3712, KC = 3072, CH = 512;

  // workspace layout (~139 MB)
  unsigned short* QT  = (unsigned short*)d_ws;   // (MP, KC) bf16: [20*w0*qf4n | 20*w1*qf3n]
  unsigned short* ST0 = QT  + MP * KC;           // (MP, KC) bf16 support b=0
  unsigned short* ST1 = ST0 + MP * KC;           // b=1
  unsigned short* V0  = ST1 + MP * KC;           // (CH, MP) bf16 f_s b=0
  unsigned short* V1  = V0  + CH * MP;
  float* logits = (float*)(V1 + CH * MP);        // (MP, MP) fp32, reused per batch;
                                                 // softmax rewrites rows as bf16 in place
  float* P    = logits + MP * MP;                // (MP, CH) fp32, accumulated over batches
  float* invn = P + MP * CH;                     // 6 slices x 3600

  // zero pads (rows >=3600 of QT/ST; whole V buffers)
  hipMemsetAsync(QT  + HW * KC, 0, (MP - HW) * KC * 2, stream);
  hipMemsetAsync(ST0 + HW * KC, 0, (MP - HW) * KC * 2, stream);
  hipMemsetAsync(ST1 + HW * KC, 0, (MP - HW) * KC * 2, stream);
  hipMemsetAsync(V0, 0, 2 * CH * MP * 2, stream);

  // norms: slices 0..5 = fq4, fs4b0, fs4b1, fq3, fs3b0, fs3b1
  colnorm_inv_k<<<57, 256, 0, stream>>>(fq4,             invn + 0 * HW, 2048);
  colnorm_inv_k<<<57, 256, 0, stream>>>(fs4,             invn + 1 * HW, 2048);
  colnorm_inv_k<<<57, 256, 0, stream>>>(fs4 + 2048 * HW, invn + 2 * HW, 2048);
  colnorm_inv_k<<<57, 256, 0, stream>>>(fq3,             invn + 3 * HW, 1024);
  colnorm_inv_k<<<57, 256, 0, stream>>>(fs3,             invn + 4 * HW, 1024);
  colnorm_inv_k<<<57, 256, 0, stream>>>(fs3 + 1024 * HW, invn + 5 * HW, 1024);

  dim3 tb(32, 8);
  // query side folds TEMP*w_chan
  tpose_k<<<dim3(113, 64), tb, 0, stream>>>(fq4,             invn + 0 * HW, wch,  0, QT, 0);
  tpose_k<<<dim3(113, 32), tb, 0, stream>>>(fq3,             invn + 3 * HW, wch,  1, QT, 2048);
  tpose_k<<<dim3(113, 64), tb, 0, stream>>>(fs4,             invn + 1 * HW, wch, -1, ST0, 0);
  tpose_k<<<dim3(113, 64), tb, 0, stream>>>(fs4 + 2048 * HW, invn + 2 * HW, wch, -1, ST1, 0);
  tpose_k<<<dim3(113, 32), tb, 0, stream>>>(fs3,             invn + 4 * HW, wch, -1, ST0, 2048);
  tpose_k<<<dim3(113, 32), tb, 0, stream>>>(fs3 + 1024 * HW, invn + 5 * HW, wch, -1, ST1, 2048);

  castv_k<<<7200, 256, 0, stream>>>(f_s,           V0);
  castv_k<<<7200, 256, 0, stream>>>(f_s + CH * HW, V1);

  for (int b = 0; b < 2; ++b) {
    const unsigned short* ST = b ? ST1 : ST0;
    const unsigned short* V  = b ? V1  : V0;
    // logits[q][s] = sum_k QT[q][k] * ST[s][k]   (includes TEMP and w_chan)
    gemm_bt_k<<<dim3(29, 29), 256, 0, stream>>>(QT, ST, logits, 3072, 3072, 3072, 3712, 0);
    // softmax rows -> bf16 attn in place (row stride 7424 bf16 elems)
    softmax_rows_k<<<3600, 256, 0, stream>>>(logits);
    // P[q][c] (+)= sum_s attn[q][s] * V[c][s]
    gemm_bt_k<<<dim3(29, 4), 256, 0, stream>>>((const unsigned short*)logits, V, P,
                                               3712, 7424, 3712, 512, b);
  }

  final_blend_k<<<dim3(113, 16), tb, 0, stream>>>(P, f_q, out);
}

// Round 2
// 746.192 us; speedup vs baseline: 1.7956x; 1.7956x over previous
//
#include <hip/hip_runtime.h>
#include <cstdint>

#define TEMP_C 20.0f

typedef float f32x4 __attribute__((ext_vector_type(4)));
typedef __bf16 bf16x8 __attribute__((ext_vector_type(8)));

// fp32 -> bf16 round-to-nearest-even
__device__ __forceinline__ unsigned short f2bf(float f) {
  union { float f; unsigned int u; } v; v.f = f;
  unsigned int r = v.u + 0x7FFFu + ((v.u >> 16) & 1u);
  return (unsigned short)(r >> 16);
}

// async global->LDS, 16B per lane (dest must be wave-uniform base + lane*16)
__device__ __forceinline__ void gload_lds16(const void* g, void* l) {
#if defined(__has_builtin) && __has_builtin(__builtin_amdgcn_global_load_lds)
  __builtin_amdgcn_global_load_lds(
      (__attribute__((address_space(1))) void*)(g),
      (__attribute__((address_space(3))) void*)(l), 16, 0, 0);
#else
  *(uint4*)l = *(const uint4*)g;
#endif
}

// ---------------------------------------------------------------------------
// 1a) partial sum-of-squares over a channel chunk.
//     grid: (57 pixel-blocks, nchunk channel-chunks). 256 thr = 64 pix x 4 subs.
//     part[chunk*3600 + p] = sum over chunk's channels of X[c][p]^2. Deterministic.
__global__ __launch_bounds__(256) void colnorm_part_k(
    const float* __restrict__ X, float* __restrict__ part, int C, int nchunk)
{
  __shared__ float red[4][64];
  const int pix = threadIdx.x & 63;
  const int sub = threadIdx.x >> 6;
  const int p = blockIdx.x * 64 + pix;
  const int cpc = C / nchunk;
  const int c0 = blockIdx.y * cpc;
  float s = 0.f;
  if (p < 3600) {
    for (int c = c0 + sub; c < c0 + cpc; c += 4) {
      float v = X[(size_t)c * 3600 + p];
      s += v * v;
    }
  }
  red[sub][pix] = s;
  __syncthreads();
  if (sub == 0 && p < 3600) {
    part[(size_t)blockIdx.y * 3600 + p] =
        red[0][pix] + red[1][pix] + red[2][pix] + red[3][pix];
  }
}

// 1b) finish: invn[p] = 1/max(sqrt(sum_j part[j][p]), 1e-12)
__global__ __launch_bounds__(256) void colnorm_fin_k(
    const float* __restrict__ part, float* __restrict__ invn, int nchunk)
{
  const int p = blockIdx.x * 256 + threadIdx.x;
  if (p >= 3600) return;
  float s = 0.f;
  for (int j = 0; j < nchunk; ++j) s += part[(size_t)j * 3600 + p];
  invn[p] = 1.0f / fmaxf(sqrtf(s), 1e-12f);
}

// ---------------------------------------------------------------------------
// 2) transpose + scale + bf16 cast: T[p][cdst0+c] = bf16(X[c][p] * invn[p] * mult)
//    T has row stride 3072 (K-contiguous for the GEMM). mult = TEMP*w_chan[widx] or 1.
__global__ __launch_bounds__(256) void tpose_k(
    const float* __restrict__ X, const float* __restrict__ invn,
    const float* __restrict__ wch, int widx,
    unsigned short* __restrict__ T, int cdst0)
{
  __shared__ float tile[32][33];
  const int tx = threadIdx.x, ty = threadIdx.y;
  const int p0 = blockIdx.x * 32, c0 = blockIdx.y * 32;
  const float mult = (widx >= 0) ? TEMP_C * wch[widx] : 1.0f;
  #pragma unroll
  for (int i = 0; i < 4; ++i) {
    int c = c0 + ty + i * 8, p = p0 + tx;
    tile[ty + i * 8][tx] = (p < 3600) ? X[(size_t)c * 3600 + p] : 0.f;
  }
  __syncthreads();
  #pragma unroll
  for (int i = 0; i < 4; ++i) {
    int p = p0 + ty + i * 8;
    if (p < 3600) {
      float sc = invn[p] * mult;
      T[(size_t)p * 3072 + cdst0 + c0 + tx] = f2bf(tile[tx][ty + i * 8] * sc);
    }
  }
}

// ---------------------------------------------------------------------------
// 3) V cast: f_s (512, 3600) fp32 -> V (512, 3712) bf16 (pad pre-zeroed)
__global__ void castv_k(const float* __restrict__ X, unsigned short* __restrict__ V)
{
  int i = blockIdx.x * 256 + threadIdx.x;
  if (i >= 512 * 3600) return;
  int c = i / 3600, s = i - c * 3600;
  V[(size_t)c * 3712 + s] = f2bf(X[i]);
}

// ---------------------------------------------------------------------------
// 4) GEMM: C[m][n] (+)= sum_k A[m][k]*B[n][k], bf16 in / fp32 out.
//    128x128 tile, BK=32, 4 waves (2x2 of 64x64), mfma_f32_16x16x32_bf16.
//    M,N must be multiples of 128; K multiple of 32. Single-buffered LDS,
//    global_load_lds staging (m97 structure).
__global__ __launch_bounds__(256) void gemm_bt_k(
    const unsigned short* __restrict__ A, const unsigned short* __restrict__ B,
    float* __restrict__ C, int K, int lda, int ldb, int ldc, int accumulate)
{
  __shared__ __align__(16) unsigned short As[128 * 32];
  __shared__ __align__(16) unsigned short Bs[128 * 32];
  const int tid = threadIdx.x;
  const int lane = tid & 63;
  const int wave = tid >> 6;
  const int wm = (wave >> 1) * 64;   // wave's 64x64 quadrant
  const int wn = (wave & 1) * 64;
  const long Arow0 = (long)blockIdx.x * 128;
  const long Brow0 = (long)blockIdx.y * 128;

  f32x4 acc[4][4] = {};

  const int r  = lane & 15;          // fragment row/col within 16
  const int kb = (lane >> 4) * 8;    // fragment k-base (8 contiguous bf16)

  for (int k0 = 0; k0 < K; k0 += 32) {
    // stage A(128x32) and B(128x32): 8 chunks of 1KB each, 2 passes x 4 waves
    #pragma unroll
    for (int pass = 0; pass < 2; ++pass) {
      const int chunk = pass * 4 + wave;
      const int m  = chunk * 16 + (lane >> 2);
      const int ke = (lane & 3) * 8;
      gload_lds16(A + (Arow0 + m) * (long)lda + k0 + ke, &As[chunk * 512 + lane * 8]);
      gload_lds16(B + (Brow0 + m) * (long)ldb + k0 + ke, &Bs[chunk * 512 + lane * 8]);
    }
    __syncthreads();  // compiler drains vmcnt(0) here

    bf16x8 af[4], bfr[4];
    #pragma unroll
    for (int f = 0; f < 4; ++f) {
      af[f]  = *(const bf16x8*)&As[(wm + f * 16 + r) * 32 + kb];
      bfr[f] = *(const bf16x8*)&Bs[(wn + f * 16 + r) * 32 + kb];
    }
    #pragma unroll
    for (int i = 0; i < 4; ++i)
      #pragma unroll
      for (int j = 0; j < 4; ++j)
        acc[i][j] = __builtin_amdgcn_mfma_f32_16x16x32_bf16(af[i], bfr[j], acc[i][j], 0, 0, 0);
    __syncthreads();
  }

  // epilogue: D row = (lane>>4)*4 + reg, col = lane&15  [verified C/D layout]
  const int rb = (lane >> 4) * 4;
  const int cn = lane & 15;
  #pragma unroll
  for (int i = 0; i < 4; ++i) {
    #pragma unroll
    for (int ii = 0; ii < 4; ++ii) {
      long m = Arow0 + wm + i * 16 + rb + ii;
      float* cp = C + m * (long)ldc + Brow0 + wn + cn;
      #pragma unroll
      for (int j = 0; j < 4; ++j) {
        float v = acc[i][j][ii];
        if (accumulate) cp[j * 16] += v; else cp[j * 16] = v;
      }
    }
  }
}

// ---------------------------------------------------------------------------
// 5) row softmax over s<3600, written IN-PLACE as bf16 into the fp32 row
//    (row byte stride 3712*4; bf16 row occupies first 7424 bytes -> lda=7424).
//    Also zeroes bf16 pad s in [3600,3712).
__global__ __launch_bounds__(256) void softmax_rows_k(float* __restrict__ logits)
{
  const int q = blockIdx.x;
  float* row = logits + (size_t)q * 3712;
  unsigned short* orow = (unsigned short*)row;
  const int tid = threadIdx.x;
  float v[15];
  float mx = -1e30f;
  #pragma unroll
  for (int j = 0; j < 15; ++j) {
    int s = tid + j * 256;
    float x = (s < 3600) ? row[s] : -1e30f;
    v[j] = x;
    mx = fmaxf(mx, x);
  }
  #pragma unroll
  for (int o = 32; o > 0; o >>= 1) mx = fmaxf(mx, __shfl_xor(mx, o));
  __shared__ float wmax[4], wsum[4];
  if ((tid & 63) == 0) wmax[tid >> 6] = mx;
  __syncthreads();
  mx = fmaxf(fmaxf(wmax[0], wmax[1]), fmaxf(wmax[2], wmax[3]));
  float sum = 0.f;
  #pragma unroll
  for (int j = 0; j < 15; ++j) {
    int s = tid + j * 256;
    float e = (s < 3600) ? __expf(v[j] - mx) : 0.f;
    v[j] = e;
    sum += e;
  }
  #pragma unroll
  for (int o = 32; o > 0; o >>= 1) sum += __shfl_xor(sum, o);
  if ((tid & 63) == 0) wsum[tid >> 6] = sum;
  __syncthreads();  // also orders: all row reads above happen before writes below
  sum = wsum[0] + wsum[1] + wsum[2] + wsum[3];
  const float inv = 1.0f / sum;
  #pragma unroll
  for (int j = 0; j < 15; ++j) {
    int s = tid + j * 256;
    if (s < 3600) orow[s] = f2bf(v[j] * inv);
    else if (s < 3712) orow[s] = 0;
  }
}

// ---------------------------------------------------------------------------
// 6) out[c][p] = 0.5*f_q[c][p] + 0.25*P[p][c]   (P = att0+att1, mean/2 * ATT_WT)
__global__ __launch_bounds__(256) void final_blend_k(
    const float* __restrict__ P, const float* __restrict__ fq, float* __restrict__ out)
{
  __shared__ float t[32][33];
  const int tx = threadIdx.x, ty = threadIdx.y;
  const int p0 = blockIdx.x * 32, c0 = blockIdx.y * 32;
  #pragma unroll
  for (int i = 0; i < 4; ++i) {
    int p = p0 + ty + i * 8, c = c0 + tx;
    t[ty + i * 8][tx] = (p < 3600) ? P[(size_t)p * 512 + c] : 0.f;
  }
  __syncthreads();
  #pragma unroll
  for (int i = 0; i < 4; ++i) {
    int c = c0 + ty + i * 8, p = p0 + tx;
    if (p < 3600) {
      size_t o = (size_t)c * 3600 + p;
      out[o] = 0.5f * fq[o] + 0.25f * t[tx][ty + i * 8];
    }
  }
}

// ---------------------------------------------------------------------------
extern "C" void kernel_launch(void* const* d_in, const int* in_sizes, int n_in,
                              void* d_out, int out_size, void* d_ws, size_t ws_size,
                              hipStream_t stream) {
  const float* fq3 = (const float*)d_in[0];  // (1,1024,60,60)
  const float* fq4 = (const float*)d_in[1];  // (1,2048,60,60)
  const float* fs3 = (const float*)d_in[2];  // (2,1024,60,60)
  const float* fs4 = (const float*)d_in[3];  // (2,2048,60,60)
  const float* f_q = (const float*)d_in[4];  // (1,512,60,60)
  const float* f_s = (const float*)d_in[5];  // (2,512,60,60)
  const float* wch = (const float*)d_in[6];  // (2,)
  float* out = (float*)d_out;

  const size_t HW = 3600, MP = 3712, KC = 3072, CH = 512;

  // workspace layout (~139 MB)
  unsigned short* QT  = (unsigned short*)d_ws;   // (MP, KC) bf16: [20*w0*qf4n | 20*w1*qf3n]
  unsigned short* ST0 = QT  + MP * KC;           // (MP, KC) bf16 support b=0
  unsigned short* ST1 = ST0 + MP * KC;           // b=1
  unsigned short* V0  = ST1 + MP * KC;           // (CH, MP) bf16 f_s b=0
  unsigned short* V1  = V0  + CH * MP;
  float* logits = (float*)(V1 + CH * MP);        // (MP, MP) fp32, reused per batch;
                                                 // softmax rewrites rows as bf16 in place
  float* P    = logits + MP * MP;                // (MP, CH) fp32, accumulated over batches
  float* invn = P + MP * CH;                     // 6 slices x 3600

  // norm partials use the (still-unused) logits region as scratch:
  // 6 slices x 16 chunks x 3600 floats = 1.38 MB << 55 MB. Norm kernels all
  // complete (same stream) before the first GEMM writes logits.
  float* part = logits;

  // zero pads (rows >=3600 of QT/ST; whole V buffers)
  hipMemsetAsync(QT  + HW * KC, 0, (MP - HW) * KC * 2, stream);
  hipMemsetAsync(ST0 + HW * KC, 0, (MP - HW) * KC * 2, stream);
  hipMemsetAsync(ST1 + HW * KC, 0, (MP - HW) * KC * 2, stream);
  hipMemsetAsync(V0, 0, 2 * CH * MP * 2, stream);

  // norms: slices 0..5 = fq4, fs4b0, fs4b1, fq3, fs3b0, fs3b1
  const int NCH = 16;  // channel chunks -> 57*16 = 912 blocks per slice
  const float* srcs[6] = {fq4, fs4, fs4 + 2048 * HW, fq3, fs3, fs3 + 1024 * HW};
  const int    Cs[6]   = {2048, 2048, 2048, 1024, 1024, 1024};
  for (int i = 0; i < 6; ++i) {
    float* ps = part + (size_t)i * NCH * HW;
    colnorm_part_k<<<dim3(57, NCH), 256, 0, stream>>>(srcs[i], ps, Cs[i], NCH);
    colnorm_fin_k<<<15, 256, 0, stream>>>(ps, invn + (size_t)i * HW, NCH);
  }

  dim3 tb(32, 8);
  // query side folds TEMP*w_chan
  tpose_k<<<dim3(113, 64), tb, 0, stream>>>(fq4,             invn + 0 * HW, wch,  0, QT, 0);
  tpose_k<<<dim3(113, 32), tb, 0, stream>>>(fq3,             invn + 3 * HW, wch,  1, QT, 2048);
  tpose_k<<<dim3(113, 64), tb, 0, stream>>>(fs4,             invn + 1 * HW, wch, -1, ST0, 0);
  tpose_k<<<dim3(113, 64), tb, 0, stream>>>(fs4 + 2048 * HW, invn + 2 * HW, wch, -1, ST1, 0);
  tpose_k<<<dim3(113, 32), tb, 0, stream>>>(fs3,             invn + 4 * HW, wch, -1, ST0, 2048);
  tpose_k<<<dim3(113, 32), tb, 0, stream>>>(fs3 + 1024 * HW, invn + 5 * HW, wch, -1, ST1, 2048);

  castv_k<<<7200, 256, 0, stream>>>(f_s,           V0);
  castv_k<<<7200, 256, 0, stream>>>(f_s + CH * HW, V1);

  for (int b = 0; b < 2; ++b) {
    const unsigned short* ST = b ? ST1 : ST0;
    const unsigned short* V  = b ? V1  : V0;
    // logits[q][s] = sum_k QT[q][k] * ST[s][k]   (includes TEMP and w_chan)
    gemm_bt_k<<<dim3(29, 29), 256, 0, stream>>>(QT, ST, logits, 3072, 3072, 3072, 3712, 0);
    // softmax rows -> bf16 attn in place (row stride 7424 bf16 elems)
    softmax_rows_k<<<3600, 256, 0, stream>>>(logits);
    // P[q][c] (+)= sum_s attn[q][s] * V[c][s]
    gemm_bt_k<<<dim3(29, 4), 256, 0, stream>>>((const unsigned short*)logits, V, P,
                                               3712, 7424, 3712, 512, b);
  }

  final_blend_k<<<dim3(113, 16), tb, 0, stream>>>(P, f_q, out);
}

// Round 3
// 674.231 us; speedup vs baseline: 1.9873x; 1.1067x over previous
//
#include <hip/hip_runtime.h>
#include <cstdint>

#define TEMP_C 20.0f

typedef float f32x4 __attribute__((ext_vector_type(4)));
typedef __bf16 bf16x8 __attribute__((ext_vector_type(8)));

// fp32 -> bf16 round-to-nearest-even
__device__ __forceinline__ unsigned short f2bf(float f) {
  union { float f; unsigned int u; } v; v.f = f;
  unsigned int r = v.u + 0x7FFFu + ((v.u >> 16) & 1u);
  return (unsigned short)(r >> 16);
}

// async global->LDS, 16B per lane (dest = wave-uniform base + lane*16)
__device__ __forceinline__ void gload_lds16(const void* g, void* l) {
#if defined(__has_builtin) && __has_builtin(__builtin_amdgcn_global_load_lds)
  __builtin_amdgcn_global_load_lds(
      (__attribute__((address_space(1))) void*)(g),
      (__attribute__((address_space(3))) void*)(l), 16, 0, 0);
#else
  *(uint4*)l = *(const uint4*)g;
#endif
}

// ---------------------------------------------------------------------------
// 1a) partial sum-of-squares over a channel chunk (deterministic, no atomics)
__global__ __launch_bounds__(256) void colnorm_part_k(
    const float* __restrict__ X, float* __restrict__ part, int C, int nchunk)
{
  __shared__ float red[4][64];
  const int pix = threadIdx.x & 63;
  const int sub = threadIdx.x >> 6;
  const int p = blockIdx.x * 64 + pix;
  const int cpc = C / nchunk;
  const int c0 = blockIdx.y * cpc;
  float s = 0.f;
  if (p < 3600) {
    for (int c = c0 + sub; c < c0 + cpc; c += 4) {
      float v = X[(size_t)c * 3600 + p];
      s += v * v;
    }
  }
  red[sub][pix] = s;
  __syncthreads();
  if (sub == 0 && p < 3600) {
    part[(size_t)blockIdx.y * 3600 + p] =
        red[0][pix] + red[1][pix] + red[2][pix] + red[3][pix];
  }
}

// 1b) finish: invn[p] = 1/max(sqrt(sum_j part[j][p]), 1e-12)
__global__ __launch_bounds__(256) void colnorm_fin_k(
    const float* __restrict__ part, float* __restrict__ invn, int nchunk)
{
  const int p = blockIdx.x * 256 + threadIdx.x;
  if (p >= 3600) return;
  float s = 0.f;
  for (int j = 0; j < nchunk; ++j) s += part[(size_t)j * 3600 + p];
  invn[p] = 1.0f / fmaxf(sqrtf(s), 1e-12f);
}

// ---------------------------------------------------------------------------
// 2) transpose + scale + bf16 cast: T[p][cdst0+c] = bf16(X[c][p]*invn[p]*mult)
__global__ __launch_bounds__(256) void tpose_k(
    const float* __restrict__ X, const float* __restrict__ invn,
    const float* __restrict__ wch, int widx,
    unsigned short* __restrict__ T, int cdst0)
{
  __shared__ float tile[32][33];
  const int tx = threadIdx.x, ty = threadIdx.y;
  const int p0 = blockIdx.x * 32, c0 = blockIdx.y * 32;
  const float mult = (widx >= 0) ? TEMP_C * wch[widx] : 1.0f;
  #pragma unroll
  for (int i = 0; i < 4; ++i) {
    int c = c0 + ty + i * 8, p = p0 + tx;
    tile[ty + i * 8][tx] = (p < 3600) ? X[(size_t)c * 3600 + p] : 0.f;
  }
  __syncthreads();
  #pragma unroll
  for (int i = 0; i < 4; ++i) {
    int p = p0 + ty + i * 8;
    if (p < 3600) {
      float sc = invn[p] * mult;
      T[(size_t)p * 3072 + cdst0 + c0 + tx] = f2bf(tile[tx][ty + i * 8] * sc);
    }
  }
}

// ---------------------------------------------------------------------------
// 3) V cast: f_s (512, 3600) fp32 -> V (512, 3840) bf16 (pad pre-zeroed)
__global__ void castv_k(const float* __restrict__ X, unsigned short* __restrict__ V)
{
  int i = blockIdx.x * 256 + threadIdx.x;
  if (i >= 512 * 3600) return;
  int c = i / 3600, s = i - c * 3600;
  V[(size_t)c * 3840 + s] = f2bf(X[i]);
}

// ---------------------------------------------------------------------------
// 4) 256x256 deep-pipelined GEMM: C[m][n] = sum_k A[m][k]*B[n][k].
//    512 thr = 8 waves (2M x 4N), per-wave 128x64 output, acc f32x4[8][4].
//    K processed in 32-wide phases; LDS = 4 slots x [256 rows][32 k] per
//    operand (128 KiB total). Prefetch distance 3 phases via global_load_lds;
//    steady-state s_waitcnt vmcnt(12) (3 halves in flight, never drains to 0);
//    raw s_barrier (no compiler vmcnt(0) drain); setprio around MFMA cluster.
//    k-major 64B-row layout => staging writes and ds_read_b128 both bank-uniform.
__global__ __launch_bounds__(512, 2) void gemm256_k(
    const unsigned short* __restrict__ A, const unsigned short* __restrict__ B,
    float* __restrict__ C, int K, int lda, int ldb, int ldc, int nbn)
{
  __shared__ __align__(16) unsigned short As[4][256 * 32];
  __shared__ __align__(16) unsigned short Bs[4][256 * 32];

  const int tid  = threadIdx.x;
  const int lane = tid & 63;
  const int wave = tid >> 6;
  const int wrow = wave >> 2;   // 0..1  (M half)
  const int wcol = wave & 3;    // 0..3  (N quarter)

  // XCD-aware bijective block remap (m204)
  const int nwg = gridDim.x;
  const int q8 = nwg >> 3, r8 = nwg & 7;
  const int xcd = blockIdx.x & 7, bidx = blockIdx.x >> 3;
  const int wg = (xcd < r8 ? xcd * (q8 + 1) : r8 * (q8 + 1) + (xcd - r8) * q8) + bidx;
  const long Arow0 = (long)(wg / nbn) * 256;
  const long Brow0 = (long)(wg % nbn) * 256;

  // per-thread staging chunks: c = qq*512+tid ; row=c>>2, kgroup=c&3 (16B)
  const unsigned short* srcA0; const unsigned short* srcA1;
  const unsigned short* srcB0; const unsigned short* srcB1;
  {
    int c0 = tid,        r0 = c0 >> 2, g0 = c0 & 3;
    int c1 = 512 + tid,  r1 = c1 >> 2, g1 = c1 & 3;
    srcA0 = A + (Arow0 + r0) * (long)lda + g0 * 8;
    srcA1 = A + (Arow0 + r1) * (long)lda + g1 * 8;
    srcB0 = B + (Brow0 + r0) * (long)ldb + g0 * 8;
    srcB1 = B + (Brow0 + r1) * (long)ldb + g1 * 8;
  }
  const int dst0 = tid * 8;           // ushort idx of chunk 0 (16B)
  const int dst1 = (512 + tid) * 8;

  #define STAGE(h) do {                                   \
    const int _s = (h) & 3; const int _ko = (h) * 32;     \
    gload_lds16(srcA0 + _ko, &As[_s][dst0]);              \
    gload_lds16(srcA1 + _ko, &As[_s][dst1]);              \
    gload_lds16(srcB0 + _ko, &Bs[_s][dst0]);              \
    gload_lds16(srcB1 + _ko, &Bs[_s][dst1]);              \
  } while (0)

  const int ln15 = lane & 15, lnk = lane >> 4;
  const int aoff = (wrow * 128 + ln15) * 32 + lnk * 8;
  const int boff = (wcol * 64 + ln15) * 32 + lnk * 8;

  f32x4 acc[8][4] = {};
  const int NH = K >> 5;   // 32-wide k-phases

  STAGE(0); STAGE(1); STAGE(2);

  for (int h = 0; h < NH; ++h) {
    if (h + 3 < NH) {
      STAGE(h + 3);
      asm volatile("s_waitcnt vmcnt(12)" ::: "memory");   // half h landed; 3 in flight
    } else {
      const int rem = NH - 1 - h;
      if (rem == 2)      asm volatile("s_waitcnt vmcnt(8)" ::: "memory");
      else if (rem == 1) asm volatile("s_waitcnt vmcnt(4)" ::: "memory");
      else               asm volatile("s_waitcnt vmcnt(0)" ::: "memory");
    }
    asm volatile("s_barrier" ::: "memory");   // all waves: slot h&3 fully staged

    const int slot = h & 3;
    bf16x8 a[8], b[4];
    #pragma unroll
    for (int i = 0; i < 8; ++i) a[i] = *(const bf16x8*)&As[slot][aoff + i * 512];
    #pragma unroll
    for (int j = 0; j < 4; ++j) b[j] = *(const bf16x8*)&Bs[slot][boff + j * 512];

    asm volatile("s_waitcnt lgkmcnt(0)" ::: "memory");
    __builtin_amdgcn_sched_barrier(0);
    __builtin_amdgcn_s_setprio(1);
    #pragma unroll
    for (int i = 0; i < 8; ++i)
      #pragma unroll
      for (int j = 0; j < 4; ++j)
        acc[i][j] = __builtin_amdgcn_mfma_f32_16x16x32_bf16(a[i], b[j], acc[i][j], 0, 0, 0);
    __builtin_amdgcn_s_setprio(0);
    asm volatile("s_barrier" ::: "memory");   // frees slot h&3 for re-staging
  }
  #undef STAGE

  // epilogue: D row = (lane>>4)*4 + reg, col = lane&15
  const int rb = lnk * 4;
  #pragma unroll
  for (int i = 0; i < 8; ++i) {
    #pragma unroll
    for (int ii = 0; ii < 4; ++ii) {
      long m = Arow0 + wrow * 128 + i * 16 + rb + ii;
      float* cp = C + m * (long)ldc + Brow0 + wcol * 64 + ln15;
      #pragma unroll
      for (int j = 0; j < 4; ++j) cp[j * 16] = acc[i][j][ii];
    }
  }
}

// ---------------------------------------------------------------------------
// 5) 128x128 GEMM (m97 structure) — used for the small PV matmul.
//    C[m][n] (+)= sum_k A[m][k]*B[n][k], bf16 in / fp32 out.
__global__ __launch_bounds__(256) void gemm_bt_k(
    const unsigned short* __restrict__ A, const unsigned short* __restrict__ B,
    float* __restrict__ C, int K, int lda, int ldb, int ldc, int accumulate)
{
  __shared__ __align__(16) unsigned short As[128 * 32];
  __shared__ __align__(16) unsigned short Bs[128 * 32];
  const int tid = threadIdx.x;
  const int lane = tid & 63;
  const int wave = tid >> 6;
  const int wm = (wave >> 1) * 64;
  const int wn = (wave & 1) * 64;
  const long Arow0 = (long)blockIdx.x * 128;
  const long Brow0 = (long)blockIdx.y * 128;

  f32x4 acc[4][4] = {};
  const int r  = lane & 15;
  const int kb = (lane >> 4) * 8;

  for (int k0 = 0; k0 < K; k0 += 32) {
    #pragma unroll
    for (int pass = 0; pass < 2; ++pass) {
      const int chunk = pass * 4 + wave;
      const int m  = chunk * 16 + (lane >> 2);
      const int ke = (lane & 3) * 8;
      gload_lds16(A + (Arow0 + m) * (long)lda + k0 + ke, &As[chunk * 512 + lane * 8]);
      gload_lds16(B + (Brow0 + m) * (long)ldb + k0 + ke, &Bs[chunk * 512 + lane * 8]);
    }
    __syncthreads();

    bf16x8 af[4], bfr[4];
    #pragma unroll
    for (int f = 0; f < 4; ++f) {
      af[f]  = *(const bf16x8*)&As[(wm + f * 16 + r) * 32 + kb];
      bfr[f] = *(const bf16x8*)&Bs[(wn + f * 16 + r) * 32 + kb];
    }
    #pragma unroll
    for (int i = 0; i < 4; ++i)
      #pragma unroll
      for (int j = 0; j < 4; ++j)
        acc[i][j] = __builtin_amdgcn_mfma_f32_16x16x32_bf16(af[i], bfr[j], acc[i][j], 0, 0, 0);
    __syncthreads();
  }

  const int rb = (lane >> 4) * 4;
  const int cn = lane & 15;
  #pragma unroll
  for (int i = 0; i < 4; ++i) {
    #pragma unroll
    for (int ii = 0; ii < 4; ++ii) {
      long m = Arow0 + wm + i * 16 + rb + ii;
      float* cp = C + m * (long)ldc + Brow0 + wn + cn;
      #pragma unroll
      for (int j = 0; j < 4; ++j) {
        float v = acc[i][j][ii];
        if (accumulate) cp[j * 16] += v; else cp[j * 16] = v;
      }
    }
  }
}

// ---------------------------------------------------------------------------
// 6) row softmax over s<3600, written IN-PLACE as bf16 (row = 3840 fp32;
//    bf16 row occupies first 7680 bytes -> PV lda=7680). Pad [3600,3840)=0.
__global__ __launch_bounds__(256) void softmax_rows_k(float* __restrict__ logits)
{
  const int q = blockIdx.x;
  float* row = logits + (size_t)q * 3840;
  unsigned short* orow = (unsigned short*)row;
  const int tid = threadIdx.x;
  float v[15];
  float mx = -1e30f;
  #pragma unroll
  for (int j = 0; j < 15; ++j) {
    int s = tid + j * 256;
    float x = (s < 3600) ? row[s] : -1e30f;
    v[j] = x;
    mx = fmaxf(mx, x);
  }
  #pragma unroll
  for (int o = 32; o > 0; o >>= 1) mx = fmaxf(mx, __shfl_xor(mx, o));
  __shared__ float wmax[4], wsum[4];
  if ((tid & 63) == 0) wmax[tid >> 6] = mx;
  __syncthreads();
  mx = fmaxf(fmaxf(wmax[0], wmax[1]), fmaxf(wmax[2], wmax[3]));
  float sum = 0.f;
  #pragma unroll
  for (int j = 0; j < 15; ++j) {
    int s = tid + j * 256;
    float e = (s < 3600) ? __expf(v[j] - mx) : 0.f;
    v[j] = e;
    sum += e;
  }
  #pragma unroll
  for (int o = 32; o > 0; o >>= 1) sum += __shfl_xor(sum, o);
  if ((tid & 63) == 0) wsum[tid >> 6] = sum;
  __syncthreads();
  sum = wsum[0] + wsum[1] + wsum[2] + wsum[3];
  const float inv = 1.0f / sum;
  #pragma unroll
  for (int j = 0; j < 15; ++j) {
    int s = tid + j * 256;
    orow[s] = (s < 3600) ? f2bf(v[j] * inv) : (unsigned short)0;
  }
}

// ---------------------------------------------------------------------------
// 7) out[c][p] = 0.5*f_q[c][p] + 0.25*(P0[p][c]+P1[p][c])
__global__ __launch_bounds__(256) void final_blend_k(
    const float* __restrict__ P0, const float* __restrict__ P1,
    const float* __restrict__ fq, float* __restrict__ out)
{
  __shared__ float t[32][33];
  const int tx = threadIdx.x, ty = threadIdx.y;
  const int p0 = blockIdx.x * 32, c0 = blockIdx.y * 32;
  #pragma unroll
  for (int i = 0; i < 4; ++i) {
    int p = p0 + ty + i * 8, c = c0 + tx;
    size_t o = (size_t)p * 512 + c;
    t[ty + i * 8][tx] = (p < 3600) ? (P0[o] + P1[o]) : 0.f;
  }
  __syncthreads();
  #pragma unroll
  for (int i = 0; i < 4; ++i) {
    int c = c0 + ty + i * 8, p = p0 + tx;
    if (p < 3600) {
      size_t o = (size_t)c * 3600 + p;
      out[o] = 0.5f * fq[o] + 0.25f * t[tx][ty + i * 8];
    }
  }
}

// ---------------------------------------------------------------------------
extern "C" void kernel_launch(void* const* d_in, const int* in_sizes, int n_in,
                              void* d_out, int out_size, void* d_ws, size_t ws_size,
                              hipStream_t stream) {
  const float* fq3 = (const float*)d_in[0];
  const float* fq4 = (const float*)d_in[1];
  const float* fs3 = (const float*)d_in[2];
  const float* fs4 = (const float*)d_in[3];
  const float* f_q = (const float*)d_in[4];
  const float* f_s = (const float*)d_in[5];
  const float* wch = (const float*)d_in[6];
  float* out = (float*)d_out;

  const size_t HW = 3600, MP = 3840, KC = 3072, CH = 512;

  // workspace (~130 MB): ST single-buffered (batches serialized on stream)
  unsigned short* QT  = (unsigned short*)d_ws;   // (MP, KC) bf16, q side (TEMP*w folded)
  unsigned short* ST  = QT + MP * KC;            // (MP, KC) bf16, support (per batch)
  unsigned short* V0  = ST + MP * KC;            // (CH, MP) bf16
  unsigned short* V1  = V0 + CH * MP;
  float* logits = (float*)(V1 + CH * MP);        // (MP, MP) fp32; softmax -> bf16 in place
  float* P0   = logits + MP * MP;                // (MP, CH) split-K partials
  float* P1   = P0 + MP * CH;
  float* invn = P1 + MP * CH;                    // 6 x 3600
  float* part = logits;                          // norm scratch (consumed pre-GEMM)

  hipMemsetAsync(QT + HW * KC, 0, (MP - HW) * KC * 2, stream);
  hipMemsetAsync(ST + HW * KC, 0, (MP - HW) * KC * 2, stream);
  hipMemsetAsync(V0, 0, 2 * CH * MP * 2, stream);

  const int NCH = 16;
  const float* srcs[6] = {fq4, fs4, fs4 + 2048 * HW, fq3, fs3, fs3 + 1024 * HW};
  const int    Cs[6]   = {2048, 2048, 2048, 1024, 1024, 1024};
  for (int i = 0; i < 6; ++i) {
    float* ps = part + (size_t)i * NCH * HW;
    colnorm_part_k<<<dim3(57, NCH), 256, 0, stream>>>(srcs[i], ps, Cs[i], NCH);
    colnorm_fin_k<<<15, 256, 0, stream>>>(ps, invn + (size_t)i * HW, NCH);
  }

  dim3 tb(32, 8);
  tpose_k<<<dim3(113, 64), tb, 0, stream>>>(fq4, invn + 0 * HW, wch, 0, QT, 0);
  tpose_k<<<dim3(113, 32), tb, 0, stream>>>(fq3, invn + 3 * HW, wch, 1, QT, 2048);
  castv_k<<<7200, 256, 0, stream>>>(f_s,           V0);
  castv_k<<<7200, 256, 0, stream>>>(f_s + CH * HW, V1);

  for (int b = 0; b < 2; ++b) {
    const float* s4 = fs4 + (size_t)b * 2048 * HW;
    const float* s3 = fs3 + (size_t)b * 1024 * HW;
    tpose_k<<<dim3(113, 64), tb, 0, stream>>>(s4, invn + (1 + b) * HW, wch, -1, ST, 0);
    tpose_k<<<dim3(113, 32), tb, 0, stream>>>(s3, invn + (4 + b) * HW, wch, -1, ST, 2048);

    // logits[q][s] = sum_k QT[q][k]*ST[s][k]  (15x15=225 blocks, 512 thr)
    gemm256_k<<<225, 512, 0, stream>>>(QT, ST, logits, 3072, 3072, 3072, 3840, 15);

    softmax_rows_k<<<3600, 256, 0, stream>>>(logits);

    // PV split-K=2: Pz[q][c] (+)= sum_{s in half z} attn[q][s]*V[c][s]
    const unsigned short* attn = (const unsigned short*)logits;  // lda 7680
    const unsigned short* V = b ? V1 : V0;
    gemm_bt_k<<<dim3(30, 4), 256, 0, stream>>>(attn,        V,        P0, 1920, 7680, 3840, 512, b);
    gemm_bt_k<<<dim3(30, 4), 256, 0, stream>>>(attn + 1920, V + 1920, P1, 1920, 7680, 3840, 512, b);
  }

  final_blend_k<<<dim3(113, 16), tb, 0, stream>>>(P0, P1, f_q, out);
}

// Round 4
// 443.870 us; speedup vs baseline: 3.0186x; 1.5190x over previous
//
#include <hip/hip_runtime.h>
#include <cstdint>

#define TEMP_C 20.0f

typedef float f32x4 __attribute__((ext_vector_type(4)));
typedef __bf16 bf16x8 __attribute__((ext_vector_type(8)));

// fp32 -> bf16 round-to-nearest-even
__device__ __forceinline__ unsigned short f2bf(float f) {
  union { float f; unsigned int u; } v; v.f = f;
  unsigned int r = v.u + 0x7FFFu + ((v.u >> 16) & 1u);
  return (unsigned short)(r >> 16);
}

// async global->LDS, 16B per lane (dest = wave-uniform base + lane*16)
__device__ __forceinline__ void gload_lds16(const void* g, void* l) {
  __builtin_amdgcn_global_load_lds(
      (__attribute__((address_space(1))) void*)(g),
      (__attribute__((address_space(3))) void*)(l), 16, 0, 0);
}

// ---------------------------------------------------------------------------
// 1a) partial sum-of-squares, all 6 feature slices in one launch.
//     slices: 0=fq4, 1=fs4b0, 2=fs4b1 (C=2048); 3=fq3, 4=fs3b0, 5=fs3b1 (C=1024)
struct Src6 { const float* p[6]; };

__global__ __launch_bounds__(256) void colnorm_part6_k(
    Src6 S, float* __restrict__ part)
{
  const int sl = blockIdx.z;
  const float* __restrict__ X = S.p[sl];
  const int C = (sl < 3) ? 2048 : 1024;
  const int cpc = C >> 4;                 // 16 chunks
  __shared__ float red[4][64];
  const int pix = threadIdx.x & 63;
  const int sub = threadIdx.x >> 6;
  const int p = blockIdx.x * 64 + pix;
  const int c0 = blockIdx.y * cpc;
  float s = 0.f;
  if (p < 3600) {
    for (int c = c0 + sub; c < c0 + cpc; c += 4) {
      float v = X[(size_t)c * 3600 + p];
      s += v * v;
    }
  }
  red[sub][pix] = s;
  __syncthreads();
  if (sub == 0 && p < 3600) {
    part[(size_t)(sl * 16 + blockIdx.y) * 3600 + p] =
        red[0][pix] + red[1][pix] + red[2][pix] + red[3][pix];
  }
}

// 1b) finish all 6 slices: invn[z][p] = 1/max(sqrt(sum_j part[z][j][p]), 1e-12)
__global__ __launch_bounds__(256) void colnorm_fin6_k(
    const float* __restrict__ part, float* __restrict__ invn)
{
  const int z = blockIdx.y;
  const int p = blockIdx.x * 256 + threadIdx.x;
  if (p >= 3600) return;
  float s = 0.f;
  #pragma unroll
  for (int j = 0; j < 16; ++j) s += part[(size_t)(z * 16 + j) * 3600 + p];
  invn[(size_t)z * 3600 + p] = 1.0f / fmaxf(sqrtf(s), 1e-12f);
}

// ---------------------------------------------------------------------------
// 2) fused transpose+scale+bf16 for BOTH pyramid levels of one feature set:
//    blockIdx.y < 64 -> level4 (C=2048, cols 0..2047), else level3 (cols 2048+)
//    T[p][cdst + c] = bf16(X[c][p] * invn[p] * mult)
__global__ __launch_bounds__(256) void tpose2_k(
    const float* __restrict__ X4, const float* __restrict__ X3,
    const float* __restrict__ i4, const float* __restrict__ i3,
    const float* __restrict__ wch, int usew, unsigned short* __restrict__ T)
{
  __shared__ float tile[32][33];
  const int tx = threadIdx.x, ty = threadIdx.y;
  const int y = blockIdx.y;
  const float* X; const float* inv; int c0, cdst; float mult;
  if (y < 64) { X = X4; inv = i4; c0 = y * 32;        cdst = c0;        mult = usew ? TEMP_C * wch[0] : 1.0f; }
  else        { X = X3; inv = i3; c0 = (y - 64) * 32; cdst = 2048 + c0; mult = usew ? TEMP_C * wch[1] : 1.0f; }
  const int p0 = blockIdx.x * 32;
  #pragma unroll
  for (int i = 0; i < 4; ++i) {
    int c = c0 + ty + i * 8, p = p0 + tx;
    tile[ty + i * 8][tx] = (p < 3600) ? X[(size_t)c * 3600 + p] : 0.f;
  }
  __syncthreads();
  #pragma unroll
  for (int i = 0; i < 4; ++i) {
    int p = p0 + ty + i * 8;
    if (p < 3600) {
      float sc = inv[p] * mult;
      T[(size_t)p * 3072 + cdst + tx] = f2bf(tile[tx][ty + i * 8] * sc);
    }
  }
}

// ---------------------------------------------------------------------------
// 3) V cast: f_s slice (512, 3600) fp32 -> V (512, 3840) bf16 (pad pre-zeroed)
__global__ void castv_k(const float* __restrict__ X, unsigned short* __restrict__ V)
{
  int i = blockIdx.x * 256 + threadIdx.x;
  if (i >= 512 * 3600) return;
  int c = i / 3600, s = i - c * 3600;
  V[(size_t)c * 3840 + s] = f2bf(X[i]);
}

// ---------------------------------------------------------------------------
// 4) 256x256 pipelined GEMM, BK=64, 2 LDS slots, XOR-swizzled LDS.
//    C[m][n] = sum_k A[m][k]*B[n][k]. 512 thr = 8 waves (2M x 4N).
//    LDS chunk layout: chunk(row,g) = row*8 + (g ^ (row&7)), g = 16B k-group.
//    -> read slot of lane = g ^ (ln15&7): 16 lanes cover 8 slots x2 = conflict-free.
//    Staging: linear LDS dest (gload_lds requirement), inverse-swizzled global src.
//    Per phase: [STAGE(h+1); vmcnt(8); barrier; read kh0; MFMA kh0; read kh1
//    (overlaps kh0 MFMA drain); MFMA kh1; barrier]. Counted vmcnt never 0 mid-loop.
__global__ __launch_bounds__(512, 2) void gemm256_k(
    const unsigned short* __restrict__ A, const unsigned short* __restrict__ B,
    float* __restrict__ C, int K, int lda, int ldb, int ldc, int nbn)
{
  __shared__ __align__(16) unsigned short As[2][256 * 64];
  __shared__ __align__(16) unsigned short Bs[2][256 * 64];

  const int tid  = threadIdx.x;
  const int lane = tid & 63;
  const int wave = tid >> 6;
  const int wrow = wave >> 2;   // 0..1
  const int wcol = wave & 3;    // 0..3

  // XCD-aware bijective block remap (m204)
  const int nwg = gridDim.x;
  const int q8 = nwg >> 3, r8 = nwg & 7;
  const int xcd = blockIdx.x & 7, bidx = blockIdx.x >> 3;
  const int wg = (xcd < r8 ? xcd * (q8 + 1) : r8 * (q8 + 1) + (xcd - r8) * q8) + bidx;
  const long Arow0 = (long)(wg / nbn) * 256;
  const long Brow0 = (long)(wg % nbn) * 256;

  // staging sources: thread handles chunks c = q*512+tid (q=0..3) per operand.
  // chunk c holds global (row=c>>3, g=(c&7)^(row&7)); LDS dest = c*16B (linear).
  const unsigned short* sA[4];
  const unsigned short* sB[4];
  #pragma unroll
  for (int q = 0; q < 4; ++q) {
    const int c = q * 512 + tid;
    const int row = c >> 3;
    const int g = (c & 7) ^ (row & 7);
    sA[q] = A + (Arow0 + row) * (long)lda + g * 8;
    sB[q] = B + (Brow0 + row) * (long)ldb + g * 8;
  }

  #define STAGE(h) do {                                          \
    const int _s = (h) & 1; const long _ko = (long)(h) * 64;     \
    _Pragma("unroll")                                            \
    for (int q = 0; q < 4; ++q) {                                \
      gload_lds16(sA[q] + _ko, &As[_s][(q * 512 + tid) * 8]);    \
      gload_lds16(sB[q] + _ko, &Bs[_s][(q * 512 + tid) * 8]);    \
    }                                                            \
  } while (0)

  // read offsets (ushort idx): frag(R, g) at R*64 + (g ^ (R&7))*8, R&7 == ln15&7
  const int ln15 = lane & 15, lnk = lane >> 4, rx = ln15 & 7;
  const int aR = wrow * 128 + ln15;
  const int bR = wcol * 64 + ln15;
  const int aoff0 = aR * 64 + ((lnk)     ^ rx) * 8;
  const int aoff1 = aR * 64 + ((lnk + 4) ^ rx) * 8;
  const int boff0 = bR * 64 + ((lnk)     ^ rx) * 8;
  const int boff1 = bR * 64 + ((lnk + 4) ^ rx) * 8;

  f32x4 acc[8][4] = {};
  const int NH = K >> 6;   // 64-wide k-phases

  STAGE(0);

  for (int h = 0; h < NH; ++h) {
    if (h + 1 < NH) {
      STAGE(h + 1);
      asm volatile("s_waitcnt vmcnt(8)" ::: "memory");  // stage h landed; h+1 in flight
    } else {
      asm volatile("s_waitcnt vmcnt(0)" ::: "memory");
    }
    asm volatile("s_barrier" ::: "memory");             // slot h&1 staged for all waves

    const int s = h & 1;
    bf16x8 a[8], bb[4];
    // k-half 0
    #pragma unroll
    for (int i = 0; i < 8; ++i) a[i]  = *(const bf16x8*)&As[s][aoff0 + i * 1024];
    #pragma unroll
    for (int j = 0; j < 4; ++j) bb[j] = *(const bf16x8*)&Bs[s][boff0 + j * 1024];
    __builtin_amdgcn_s_setprio(1);
    #pragma unroll
    for (int i = 0; i < 8; ++i)
      #pragma unroll
      for (int j = 0; j < 4; ++j)
        acc[i][j] = __builtin_amdgcn_mfma_f32_16x16x32_bf16(a[i], bb[j], acc[i][j], 0, 0, 0);
    __builtin_amdgcn_s_setprio(0);
    // k-half 1 (reads issue while kh0 MFMAs drain)
    #pragma unroll
    for (int i = 0; i < 8; ++i) a[i]  = *(const bf16x8*)&As[s][aoff1 + i * 1024];
    #pragma unroll
    for (int j = 0; j < 4; ++j) bb[j] = *(const bf16x8*)&Bs[s][boff1 + j * 1024];
    __builtin_amdgcn_s_setprio(1);
    #pragma unroll
    for (int i = 0; i < 8; ++i)
      #pragma unroll
      for (int j = 0; j < 4; ++j)
        acc[i][j] = __builtin_amdgcn_mfma_f32_16x16x32_bf16(a[i], bb[j], acc[i][j], 0, 0, 0);
    __builtin_amdgcn_s_setprio(0);
    asm volatile("s_barrier" ::: "memory");             // all reads of slot h&1 done
  }
  #undef STAGE

  // epilogue: D row = (lane>>4)*4 + reg, col = lane&15
  const int rb = lnk * 4;
  #pragma unroll
  for (int i = 0; i < 8; ++i) {
    #pragma unroll
    for (int ii = 0; ii < 4; ++ii) {
      long m = Arow0 + wrow * 128 + i * 16 + rb + ii;
      float* cp = C + m * (long)ldc + Brow0 + wcol * 64 + ln15;
      #pragma unroll
      for (int j = 0; j < 4; ++j) cp[j * 16] = acc[i][j][ii];
    }
  }
}

// ---------------------------------------------------------------------------
// 5) 128x128 GEMM (m97 structure) for PV; blockIdx.z = split-K chunk.
//    C[m][n] (+)= sum_k A[m][k+z*zk]*B[n][k+z*zk], C += z*zc.
__global__ __launch_bounds__(256) void gemm_pv_k(
    const unsigned short* __restrict__ A, const unsigned short* __restrict__ B,
    float* __restrict__ C, int K, int lda, int ldb, int ldc,
    long zk, long zc, int accumulate)
{
  A += (long)blockIdx.z * zk;
  B += (long)blockIdx.z * zk;
  C += (long)blockIdx.z * zc;
  __shared__ __align__(16) unsigned short As[128 * 32];
  __shared__ __align__(16) unsigned short Bs[128 * 32];
  const int tid = threadIdx.x;
  const int lane = tid & 63;
  const int wave = tid >> 6;
  const int wm = (wave >> 1) * 64;
  const int wn = (wave & 1) * 64;
  const long Arow0 = (long)blockIdx.x * 128;
  const long Brow0 = (long)blockIdx.y * 128;

  f32x4 acc[4][4] = {};
  const int r  = lane & 15;
  const int kb = (lane >> 4) * 8;

  for (int k0 = 0; k0 < K; k0 += 32) {
    #pragma unroll
    for (int pass = 0; pass < 2; ++pass) {
      const int chunk = pass * 4 + wave;
      const int m  = chunk * 16 + (lane >> 2);
      const int ke = (lane & 3) * 8;
      gload_lds16(A + (Arow0 + m) * (long)lda + k0 + ke, &As[chunk * 512 + lane * 8]);
      gload_lds16(B + (Brow0 + m) * (long)ldb + k0 + ke, &Bs[chunk * 512 + lane * 8]);
    }
    __syncthreads();

    bf16x8 af[4], bfr[4];
    #pragma unroll
    for (int f = 0; f < 4; ++f) {
      af[f]  = *(const bf16x8*)&As[(wm + f * 16 + r) * 32 + kb];
      bfr[f] = *(const bf16x8*)&Bs[(wn + f * 16 + r) * 32 + kb];
    }
    #pragma unroll
    for (int i = 0; i < 4; ++i)
      #pragma unroll
      for (int j = 0; j < 4; ++j)
        acc[i][j] = __builtin_amdgcn_mfma_f32_16x16x32_bf16(af[i], bfr[j], acc[i][j], 0, 0, 0);
    __syncthreads();
  }

  const int rb = (lane >> 4) * 4;
  const int cn = lane & 15;
  #pragma unroll
  for (int i = 0; i < 4; ++i) {
    #pragma unroll
    for (int ii = 0; ii < 4; ++ii) {
      long m = Arow0 + wm + i * 16 + rb + ii;
      float* cp = C + m * (long)ldc + Brow0 + wn + cn;
      #pragma unroll
      for (int j = 0; j < 4; ++j) {
        float v = acc[i][j][ii];
        if (accumulate) cp[j * 16] += v; else cp[j * 16] = v;
      }
    }
  }
}

// ---------------------------------------------------------------------------
// 6) row softmax over s<3600, written IN-PLACE as bf16 (row = 3840 fp32;
//    bf16 row = first 7680 bytes -> PV lda=7680). Pad [3600,3840)=0.
__global__ __launch_bounds__(256) void softmax_rows_k(float* __restrict__ logits)
{
  const int q = blockIdx.x;
  float* row = logits + (size_t)q * 3840;
  unsigned short* orow = (unsigned short*)row;
  const int tid = threadIdx.x;
  float v[15];
  float mx = -1e30f;
  #pragma unroll
  for (int j = 0; j < 15; ++j) {
    int s = tid + j * 256;
    float x = (s < 3600) ? row[s] : -1e30f;
    v[j] = x;
    mx = fmaxf(mx, x);
  }
  #pragma unroll
  for (int o = 32; o > 0; o >>= 1) mx = fmaxf(mx, __shfl_xor(mx, o));
  __shared__ float wmax[4], wsum[4];
  if ((tid & 63) == 0) wmax[tid >> 6] = mx;
  __syncthreads();
  mx = fmaxf(fmaxf(wmax[0], wmax[1]), fmaxf(wmax[2], wmax[3]));
  float sum = 0.f;
  #pragma unroll
  for (int j = 0; j < 15; ++j) {
    int s = tid + j * 256;
    float e = (s < 3600) ? __expf(v[j] - mx) : 0.f;
    v[j] = e;
    sum += e;
  }
  #pragma unroll
  for (int o = 32; o > 0; o >>= 1) sum += __shfl_xor(sum, o);
  if ((tid & 63) == 0) wsum[tid >> 6] = sum;
  __syncthreads();
  sum = wsum[0] + wsum[1] + wsum[2] + wsum[3];
  const float inv = 1.0f / sum;
  #pragma unroll
  for (int j = 0; j < 15; ++j) {
    int s = tid + j * 256;
    orow[s] = (s < 3600) ? f2bf(v[j] * inv) : (unsigned short)0;
  }
}

// ---------------------------------------------------------------------------
// 7) out[c][p] = 0.5*f_q[c][p] + 0.25*(P0+P1+P2)[p][c]
__global__ __launch_bounds__(256) void final_blend_k(
    const float* __restrict__ P, const float* __restrict__ fq,
    float* __restrict__ out)
{
  __shared__ float t[32][33];
  const int tx = threadIdx.x, ty = threadIdx.y;
  const int p0 = blockIdx.x * 32, c0 = blockIdx.y * 32;
  const long ZC = 3840L * 512;
  #pragma unroll
  for (int i = 0; i < 4; ++i) {
    int p = p0 + ty + i * 8, c = c0 + tx;
    size_t o = (size_t)p * 512 + c;
    t[ty + i * 8][tx] = (p < 3600) ? (P[o] + P[o + ZC] + P[o + 2 * ZC]) : 0.f;
  }
  __syncthreads();
  #pragma unroll
  for (int i = 0; i < 4; ++i) {
    int c = c0 + ty + i * 8, p = p0 + tx;
    if (p < 3600) {
      size_t o = (size_t)c * 3600 + p;
      out[o] = 0.5f * fq[o] + 0.25f * t[tx][ty + i * 8];
    }
  }
}

// ---------------------------------------------------------------------------
extern "C" void kernel_launch(void* const* d_in, const int* in_sizes, int n_in,
                              void* d_out, int out_size, void* d_ws, size_t ws_size,
                              hipStream_t stream) {
  const float* fq3 = (const float*)d_in[0];
  const float* fq4 = (const float*)d_in[1];
  const float* fs3 = (const float*)d_in[2];
  const float* fs4 = (const float*)d_in[3];
  const float* f_q = (const float*)d_in[4];
  const float* f_s = (const float*)d_in[5];
  const float* wch = (const float*)d_in[6];
  float* out = (float*)d_out;

  const size_t HW = 3600, MP = 3840, KC = 3072, CH = 512;

  // workspace (~134 MB)
  unsigned short* QT = (unsigned short*)d_ws;    // (MP, KC) bf16, query (TEMP*w folded)
  unsigned short* ST = QT + MP * KC;             // (MP, KC) bf16, support (per batch)
  unsigned short* V  = ST + MP * KC;             // (CH, MP) bf16 (per batch)
  float* logits = (float*)(V + CH * MP);         // (MP, MP) fp32; softmax -> bf16 in place
  float* P    = logits + MP * MP;                // 3 x (MP, CH) split-K partials
  float* invn = P + 3 * MP * CH;                 // 6 x 3600
  float* part = logits;                          // norm scratch (consumed pre-GEMM)

  hipMemsetAsync(QT + HW * KC, 0, (MP - HW) * KC * 2, stream);
  hipMemsetAsync(ST + HW * KC, 0, (MP - HW) * KC * 2, stream);
  hipMemsetAsync(V, 0, CH * MP * 2, stream);

  // norms (one part launch + one fin launch for all 6 slices)
  Src6 S;
  S.p[0] = fq4; S.p[1] = fs4; S.p[2] = fs4 + 2048 * HW;
  S.p[3] = fq3; S.p[4] = fs3; S.p[5] = fs3 + 1024 * HW;
  colnorm_part6_k<<<dim3(57, 16, 6), 256, 0, stream>>>(S, part);
  colnorm_fin6_k<<<dim3(15, 6), 256, 0, stream>>>(part, invn);

  dim3 tb(32, 8);
  // query side (both levels, one launch)
  tpose2_k<<<dim3(113, 96), tb, 0, stream>>>(fq4, fq3, invn + 0 * HW, invn + 3 * HW,
                                             wch, 1, QT);

  for (int b = 0; b < 2; ++b) {
    castv_k<<<7200, 256, 0, stream>>>(f_s + (size_t)b * CH * HW, V);
    tpose2_k<<<dim3(113, 96), tb, 0, stream>>>(
        fs4 + (size_t)b * 2048 * HW, fs3 + (size_t)b * 1024 * HW,
        invn + (1 + b) * HW, invn + (4 + b) * HW, wch, 0, ST);

    // logits[q][s] = sum_k QT[q][k]*ST[s][k]
    gemm256_k<<<225, 512, 0, stream>>>(QT, ST, logits, 3072, 3072, 3072, 3840, 15);

    softmax_rows_k<<<3600, 256, 0, stream>>>(logits);

    // PV split-K=3 in one launch: P[z][q][c] (+)= sum_{s in chunk z} attn[q][s]*V[c][s]
    gemm_pv_k<<<dim3(30, 4, 3), 256, 0, stream>>>(
        (const unsigned short*)logits, V, P, 1280, 7680, 3840, 512,
        1280L, 3840L * 512, b);
  }

  final_blend_k<<<dim3(113, 16), tb, 0, stream>>>(P, f_q, out);
}

// Round 5
// 422.732 us; speedup vs baseline: 3.1696x; 1.0500x over previous
//
#include <hip/hip_runtime.h>
#include <cstdint>

#define TEMP_C 20.0f

typedef float f32x4 __attribute__((ext_vector_type(4)));
typedef __bf16 bf16x8 __attribute__((ext_vector_type(8)));

// fp32 -> bf16 round-to-nearest-even
__device__ __forceinline__ unsigned short f2bf(float f) {
  union { float f; unsigned int u; } v; v.f = f;
  unsigned int r = v.u + 0x7FFFu + ((v.u >> 16) & 1u);
  return (unsigned short)(r >> 16);
}

// async global->LDS, 16B per lane (dest = wave-uniform base + lane*16)
__device__ __forceinline__ void gload_lds16(const void* g, void* l) {
  __builtin_amdgcn_global_load_lds(
      (__attribute__((address_space(1))) void*)(g),
      (__attribute__((address_space(3))) void*)(l), 16, 0, 0);
}

// ---------------------------------------------------------------------------
// 1a) partial sum-of-squares, all 6 feature slices in one launch.
struct Src6 { const float* p[6]; };

__global__ __launch_bounds__(256) void colnorm_part6_k(
    Src6 S, float* __restrict__ part)
{
  const int sl = blockIdx.z;
  const float* __restrict__ X = S.p[sl];
  const int C = (sl < 3) ? 2048 : 1024;
  const int cpc = C >> 4;                 // 16 chunks
  __shared__ float red[4][64];
  const int pix = threadIdx.x & 63;
  const int sub = threadIdx.x >> 6;
  const int p = blockIdx.x * 64 + pix;
  const int c0 = blockIdx.y * cpc;
  float s = 0.f;
  if (p < 3600) {
    for (int c = c0 + sub; c < c0 + cpc; c += 4) {
      float v = X[(size_t)c * 3600 + p];
      s += v * v;
    }
  }
  red[sub][pix] = s;
  __syncthreads();
  if (sub == 0 && p < 3600) {
    part[(size_t)(sl * 16 + blockIdx.y) * 3600 + p] =
        red[0][pix] + red[1][pix] + red[2][pix] + red[3][pix];
  }
}

// 1b) finish all 6 slices
__global__ __launch_bounds__(256) void colnorm_fin6_k(
    const float* __restrict__ part, float* __restrict__ invn)
{
  const int z = blockIdx.y;
  const int p = blockIdx.x * 256 + threadIdx.x;
  if (p >= 3600) return;
  float s = 0.f;
  #pragma unroll
  for (int j = 0; j < 16; ++j) s += part[(size_t)(z * 16 + j) * 3600 + p];
  invn[(size_t)z * 3600 + p] = 1.0f / fmaxf(sqrtf(s), 1e-12f);
}

// ---------------------------------------------------------------------------
// 2) fused transpose+scale+bf16 for BOTH pyramid levels of one feature set
__global__ __launch_bounds__(256) void tpose2_k(
    const float* __restrict__ X4, const float* __restrict__ X3,
    const float* __restrict__ i4, const float* __restrict__ i3,
    const float* __restrict__ wch, int usew, unsigned short* __restrict__ T)
{
  __shared__ float tile[32][33];
  const int tx = threadIdx.x, ty = threadIdx.y;
  const int y = blockIdx.y;
  const float* X; const float* inv; int c0, cdst; float mult;
  if (y < 64) { X = X4; inv = i4; c0 = y * 32;        cdst = c0;        mult = usew ? TEMP_C * wch[0] : 1.0f; }
  else        { X = X3; inv = i3; c0 = (y - 64) * 32; cdst = 2048 + c0; mult = usew ? TEMP_C * wch[1] : 1.0f; }
  const int p0 = blockIdx.x * 32;
  #pragma unroll
  for (int i = 0; i < 4; ++i) {
    int c = c0 + ty + i * 8, p = p0 + tx;
    tile[ty + i * 8][tx] = (p < 3600) ? X[(size_t)c * 3600 + p] : 0.f;
  }
  __syncthreads();
  #pragma unroll
  for (int i = 0; i < 4; ++i) {
    int p = p0 + ty + i * 8;
    if (p < 3600) {
      float sc = inv[p] * mult;
      T[(size_t)p * 3072 + cdst + tx] = f2bf(tile[tx][ty + i * 8] * sc);
    }
  }
}

// ---------------------------------------------------------------------------
// 3) V cast: f_s slice (512, 3600) fp32 -> V (512, 3840) bf16 (pad pre-zeroed)
__global__ void castv_k(const float* __restrict__ X, unsigned short* __restrict__ V)
{
  int i = blockIdx.x * 256 + threadIdx.x;
  if (i >= 512 * 3600) return;
  int c = i / 3600, s = i - c * 3600;
  V[(size_t)c * 3840 + s] = f2bf(X[i]);
}

// ---------------------------------------------------------------------------
// 4) 256x256 GEMM, 8-phase schedule (T3+T4+T5), BK=64, 2 LDS slots,
//    XOR-swizzled LDS (zero-conflict, verified round 4).
//    Per K-tile: 4 phases x {ds_read subtile; stage HT(t+1); barrier;
//    lgkmcnt(0)+sched_barrier; setprio(1); 16 MFMA; setprio(0); barrier}.
//    Tile t+1 staged into slot (t+1)&1 during t's phases 0-2; single
//    tile-boundary vmcnt(0) at end of phase 3 (no younger loads pending).
__global__ __launch_bounds__(512, 2) void gemm256_k(
    const unsigned short* __restrict__ A, const unsigned short* __restrict__ B,
    float* __restrict__ C, int K, int lda, int ldb, int ldc, int nbn)
{
  __shared__ __align__(16) unsigned short As[2][256 * 64];
  __shared__ __align__(16) unsigned short Bs[2][256 * 64];

  const int tid  = threadIdx.x;
  const int lane = tid & 63;
  const int wave = tid >> 6;
  const int wrow = wave >> 2;   // 0..1
  const int wcol = wave & 3;    // 0..3

  // XCD-aware bijective block remap (m204)
  const int nwg = gridDim.x;
  const int q8 = nwg >> 3, r8 = nwg & 7;
  const int xcd = blockIdx.x & 7, bidx = blockIdx.x >> 3;
  const int wg = (xcd < r8 ? xcd * (q8 + 1) : r8 * (q8 + 1) + (xcd - r8) * q8) + bidx;
  const long Arow0 = (long)(wg / nbn) * 256;
  const long Brow0 = (long)(wg % nbn) * 256;

  // staging sources: thread handles chunks c = q*512+tid (q=0..3) per operand.
  // chunk c holds global (row=c>>3, g=(c&7)^(row&7)); LDS dest = c*16B (linear).
  const unsigned short* sA[4];
  const unsigned short* sB[4];
  #pragma unroll
  for (int q = 0; q < 4; ++q) {
    const int c = q * 512 + tid;
    const int row = c >> 3;
    const int g = (c & 7) ^ (row & 7);
    sA[q] = A + (Arow0 + row) * (long)lda + g * 8;
    sB[q] = B + (Brow0 + row) * (long)ldb + g * 8;
  }

  // half-tile stages: half H of tile tt (q = 2H, 2H+1), slot = tt&1
  #define STAGE_A(tt, H) do {                                              \
    const long _ko = (long)(tt) * 64;                                      \
    gload_lds16(sA[2*(H)]   + _ko, &As[(tt)&1][((2*(H))*512   + tid)*8]);  \
    gload_lds16(sA[2*(H)+1] + _ko, &As[(tt)&1][((2*(H)+1)*512 + tid)*8]);  \
  } while (0)
  #define STAGE_B(tt, H) do {                                              \
    const long _ko = (long)(tt) * 64;                                      \
    gload_lds16(sB[2*(H)]   + _ko, &Bs[(tt)&1][((2*(H))*512   + tid)*8]);  \
    gload_lds16(sB[2*(H)+1] + _ko, &Bs[(tt)&1][((2*(H)+1)*512 + tid)*8]);  \
  } while (0)

  #define BAR   asm volatile("s_barrier" ::: "memory")
  #define LGKM0 do { asm volatile("s_waitcnt lgkmcnt(0)" ::: "memory");    \
                     __builtin_amdgcn_sched_barrier(0); } while (0)

  // read offsets (ushort idx): frag(R, g) at R*64 + (g ^ (R&7))*8
  const int ln15 = lane & 15, lnk = lane >> 4, rx = ln15 & 7;
  const int aR = wrow * 128 + ln15;
  const int bR = wcol * 64 + ln15;
  const int aoff0 = aR * 64 + ((lnk)     ^ rx) * 8;
  const int aoff1 = aR * 64 + ((lnk + 4) ^ rx) * 8;
  const int boff0 = bR * 64 + ((lnk)     ^ rx) * 8;
  const int boff1 = bR * 64 + ((lnk + 4) ^ rx) * 8;

  f32x4 acc[8][4] = {};
  const int NT = K >> 6;   // 64-wide K-tiles

  // prologue: stage tile 0 fully
  STAGE_A(0, 0); STAGE_A(0, 1); STAGE_B(0, 0); STAGE_B(0, 1);
  asm volatile("s_waitcnt vmcnt(0)" ::: "memory");
  BAR;

  for (int t = 0; t < NT; ++t) {
    const int s = t & 1;
    const bool pf = (t + 1 < NT);
    bf16x8 a[4], b[4];

    // ---- phase 0: acc rows 0-3, k-half 0
    #pragma unroll
    for (int i = 0; i < 4; ++i) a[i] = *(const bf16x8*)&As[s][aoff0 + i * 1024];
    #pragma unroll
    for (int j = 0; j < 4; ++j) b[j] = *(const bf16x8*)&Bs[s][boff0 + j * 1024];
    if (pf) { STAGE_A(t + 1, 0); STAGE_A(t + 1, 1); }
    BAR; LGKM0;
    __builtin_amdgcn_s_setprio(1);
    #pragma unroll
    for (int i = 0; i < 4; ++i)
      #pragma unroll
      for (int j = 0; j < 4; ++j)
        acc[i][j] = __builtin_amdgcn_mfma_f32_16x16x32_bf16(a[i], b[j], acc[i][j], 0, 0, 0);
    __builtin_amdgcn_s_setprio(0);
    BAR;

    // ---- phase 1: acc rows 4-7, k-half 0 (reuse b)
    #pragma unroll
    for (int i = 0; i < 4; ++i) a[i] = *(const bf16x8*)&As[s][aoff0 + (4 + i) * 1024];
    if (pf) STAGE_B(t + 1, 0);
    BAR; LGKM0;
    __builtin_amdgcn_s_setprio(1);
    #pragma unroll
    for (int i = 0; i < 4; ++i)
      #pragma unroll
      for (int j = 0; j < 4; ++j)
        acc[4 + i][j] = __builtin_amdgcn_mfma_f32_16x16x32_bf16(a[i], b[j], acc[4 + i][j], 0, 0, 0);
    __builtin_amdgcn_s_setprio(0);
    BAR;

    // ---- phase 2: acc rows 0-3, k-half 1
    #pragma unroll
    for (int i = 0; i < 4; ++i) a[i] = *(const bf16x8*)&As[s][aoff1 + i * 1024];
    #pragma unroll
    for (int j = 0; j < 4; ++j) b[j] = *(const bf16x8*)&Bs[s][boff1 + j * 1024];
    if (pf) STAGE_B(t + 1, 1);
    BAR; LGKM0;
    __builtin_amdgcn_s_setprio(1);
    #pragma unroll
    for (int i = 0; i < 4; ++i)
      #pragma unroll
      for (int j = 0; j < 4; ++j)
        acc[i][j] = __builtin_amdgcn_mfma_f32_16x16x32_bf16(a[i], b[j], acc[i][j], 0, 0, 0);
    __builtin_amdgcn_s_setprio(0);
    BAR;

    // ---- phase 3: acc rows 4-7, k-half 1 (reuse b); tile-boundary wait
    #pragma unroll
    for (int i = 0; i < 4; ++i) a[i] = *(const bf16x8*)&As[s][aoff1 + (4 + i) * 1024];
    BAR; LGKM0;
    __builtin_amdgcn_s_setprio(1);
    #pragma unroll
    for (int i = 0; i < 4; ++i)
      #pragma unroll
      for (int j = 0; j < 4; ++j)
        acc[4 + i][j] = __builtin_amdgcn_mfma_f32_16x16x32_bf16(a[i], b[j], acc[4 + i][j], 0, 0, 0);
    __builtin_amdgcn_s_setprio(0);
    asm volatile("s_waitcnt vmcnt(0)" ::: "memory");  // tile t+1 staged for all waves
    BAR;
  }
  #undef STAGE_A
  #undef STAGE_B
  #undef BAR
  #undef LGKM0

  // epilogue: D row = (lane>>4)*4 + reg, col = lane&15
  const int rb = lnk * 4;
  #pragma unroll
  for (int i = 0; i < 8; ++i) {
    #pragma unroll
    for (int ii = 0; ii < 4; ++ii) {
      long m = Arow0 + wrow * 128 + i * 16 + rb + ii;
      float* cp = C + m * (long)ldc + Brow0 + wcol * 64 + ln15;
      #pragma unroll
      for (int j = 0; j < 4; ++j) cp[j * 16] = acc[i][j][ii];
    }
  }
}

// ---------------------------------------------------------------------------
// 5) 128x128 GEMM (m97 structure) for PV; blockIdx.z = split-K chunk.
__global__ __launch_bounds__(256) void gemm_pv_k(
    const unsigned short* __restrict__ A, const unsigned short* __restrict__ B,
    float* __restrict__ C, int K, int lda, int ldb, int ldc,
    long zk, long zc, int accumulate)
{
  A += (long)blockIdx.z * zk;
  B += (long)blockIdx.z * zk;
  C += (long)blockIdx.z * zc;
  __shared__ __align__(16) unsigned short As[128 * 32];
  __shared__ __align__(16) unsigned short Bs[128 * 32];
  const int tid = threadIdx.x;
  const int lane = tid & 63;
  const int wave = tid >> 6;
  const int wm = (wave >> 1) * 64;
  const int wn = (wave & 1) * 64;
  const long Arow0 = (long)blockIdx.x * 128;
  const long Brow0 = (long)blockIdx.y * 128;

  f32x4 acc[4][4] = {};
  const int r  = lane & 15;
  const int kb = (lane >> 4) * 8;

  for (int k0 = 0; k0 < K; k0 += 32) {
    #pragma unroll
    for (int pass = 0; pass < 2; ++pass) {
      const int chunk = pass * 4 + wave;
      const int m  = chunk * 16 + (lane >> 2);
      const int ke = (lane & 3) * 8;
      gload_lds16(A + (Arow0 + m) * (long)lda + k0 + ke, &As[chunk * 512 + lane * 8]);
      gload_lds16(B + (Brow0 + m) * (long)ldb + k0 + ke, &Bs[chunk * 512 + lane * 8]);
    }
    __syncthreads();

    bf16x8 af[4], bfr[4];
    #pragma unroll
    for (int f = 0; f < 4; ++f) {
      af[f]  = *(const bf16x8*)&As[(wm + f * 16 + r) * 32 + kb];
      bfr[f] = *(const bf16x8*)&Bs[(wn + f * 16 + r) * 32 + kb];
    }
    #pragma unroll
    for (int i = 0; i < 4; ++i)
      #pragma unroll
      for (int j = 0; j < 4; ++j)
        acc[i][j] = __builtin_amdgcn_mfma_f32_16x16x32_bf16(af[i], bfr[j], acc[i][j], 0, 0, 0);
    __syncthreads();
  }

  const int rb = (lane >> 4) * 4;
  const int cn = lane & 15;
  #pragma unroll
  for (int i = 0; i < 4; ++i) {
    #pragma unroll
    for (int ii = 0; ii < 4; ++ii) {
      long m = Arow0 + wm + i * 16 + rb + ii;
      float* cp = C + m * (long)ldc + Brow0 + wn + cn;
      #pragma unroll
      for (int j = 0; j < 4; ++j) {
        float v = acc[i][j][ii];
        if (accumulate) cp[j * 16] += v; else cp[j * 16] = v;
      }
    }
  }
}

// ---------------------------------------------------------------------------
// 6) row softmax, in-place fp32 -> bf16 (row = 3840 fp32; PV lda = 7680)
__global__ __launch_bounds__(256) void softmax_rows_k(float* __restrict__ logits)
{
  const int q = blockIdx.x;
  float* row = logits + (size_t)q * 3840;
  unsigned short* orow = (unsigned short*)row;
  const int tid = threadIdx.x;
  float v[15];
  float mx = -1e30f;
  #pragma unroll
  for (int j = 0; j < 15; ++j) {
    int s = tid + j * 256;
    float x = (s < 3600) ? row[s] : -1e30f;
    v[j] = x;
    mx = fmaxf(mx, x);
  }
  #pragma unroll
  for (int o = 32; o > 0; o >>= 1) mx = fmaxf(mx, __shfl_xor(mx, o));
  __shared__ float wmax[4], wsum[4];
  if ((tid & 63) == 0) wmax[tid >> 6] = mx;
  __syncthreads();
  mx = fmaxf(fmaxf(wmax[0], wmax[1]), fmaxf(wmax[2], wmax[3]));
  float sum = 0.f;
  #pragma unroll
  for (int j = 0; j < 15; ++j) {
    int s = tid + j * 256;
    float e = (s < 3600) ? __expf(v[j] - mx) : 0.f;
    v[j] = e;
    sum += e;
  }
  #pragma unroll
  for (int o = 32; o > 0; o >>= 1) sum += __shfl_xor(sum, o);
  if ((tid & 63) == 0) wsum[tid >> 6] = sum;
  __syncthreads();
  sum = wsum[0] + wsum[1] + wsum[2] + wsum[3];
  const float inv = 1.0f / sum;
  #pragma unroll
  for (int j = 0; j < 15; ++j) {
    int s = tid + j * 256;
    orow[s] = (s < 3600) ? f2bf(v[j] * inv) : (unsigned short)0;
  }
}

// ---------------------------------------------------------------------------
// 7) out[c][p] = 0.5*f_q[c][p] + 0.25*(P0+P1+P2)[p][c]
__global__ __launch_bounds__(256) void final_blend_k(
    const float* __restrict__ P, const float* __restrict__ fq,
    float* __restrict__ out)
{
  __shared__ float t[32][33];
  const int tx = threadIdx.x, ty = threadIdx.y;
  const int p0 = blockIdx.x * 32, c0 = blockIdx.y * 32;
  const long ZC = 3840L * 512;
  #pragma unroll
  for (int i = 0; i < 4; ++i) {
    int p = p0 + ty + i * 8, c = c0 + tx;
    size_t o = (size_t)p * 512 + c;
    t[ty + i * 8][tx] = (p < 3600) ? (P[o] + P[o + ZC] + P[o + 2 * ZC]) : 0.f;
  }
  __syncthreads();
  #pragma unroll
  for (int i = 0; i < 4; ++i) {
    int c = c0 + ty + i * 8, p = p0 + tx;
    if (p < 3600) {
      size_t o = (size_t)c * 3600 + p;
      out[o] = 0.5f * fq[o] + 0.25f * t[tx][ty + i * 8];
    }
  }
}

// ---------------------------------------------------------------------------
extern "C" void kernel_launch(void* const* d_in, const int* in_sizes, int n_in,
                              void* d_out, int out_size, void* d_ws, size_t ws_size,
                              hipStream_t stream) {
  const float* fq3 = (const float*)d_in[0];
  const float* fq4 = (const float*)d_in[1];
  const float* fs3 = (const float*)d_in[2];
  const float* fs4 = (const float*)d_in[3];
  const float* f_q = (const float*)d_in[4];
  const float* f_s = (const float*)d_in[5];
  const float* wch = (const float*)d_in[6];
  float* out = (float*)d_out;

  const size_t HW = 3600, MP = 3840, KC = 3072, CH = 512;

  // workspace (~134 MB)
  unsigned short* QT = (unsigned short*)d_ws;    // (MP, KC) bf16, query (TEMP*w folded)
  unsigned short* ST = QT + MP * KC;             // (MP, KC) bf16, support (per batch)
  unsigned short* V  = ST + MP * KC;             // (CH, MP) bf16 (per batch)
  float* logits = (float*)(V + CH * MP);         // (MP, MP) fp32; softmax -> bf16 in place
  float* P    = logits + MP * MP;                // 3 x (MP, CH) split-K partials
  float* invn = P + 3 * MP * CH;                 // 6 x 3600
  float* part = logits;                          // norm scratch (consumed pre-GEMM)

  hipMemsetAsync(QT + HW * KC, 0, (MP - HW) * KC * 2, stream);
  hipMemsetAsync(ST + HW * KC, 0, (MP - HW) * KC * 2, stream);
  hipMemsetAsync(V, 0, CH * MP * 2, stream);

  Src6 S;
  S.p[0] = fq4; S.p[1] = fs4; S.p[2] = fs4 + 2048 * HW;
  S.p[3] = fq3; S.p[4] = fs3; S.p[5] = fs3 + 1024 * HW;
  colnorm_part6_k<<<dim3(57, 16, 6), 256, 0, stream>>>(S, part);
  colnorm_fin6_k<<<dim3(15, 6), 256, 0, stream>>>(part, invn);

  dim3 tb(32, 8);
  tpose2_k<<<dim3(113, 96), tb, 0, stream>>>(fq4, fq3, invn + 0 * HW, invn + 3 * HW,
                                             wch, 1, QT);

  for (int b = 0; b < 2; ++b) {
    castv_k<<<7200, 256, 0, stream>>>(f_s + (size_t)b * CH * HW, V);
    tpose2_k<<<dim3(113, 96), tb, 0, stream>>>(
        fs4 + (size_t)b * 2048 * HW, fs3 + (size_t)b * 1024 * HW,
        invn + (1 + b) * HW, invn + (4 + b) * HW, wch, 0, ST);

    gemm256_k<<<225, 512, 0, stream>>>(QT, ST, logits, 3072, 3072, 3072, 3840, 15);

    softmax_rows_k<<<3600, 256, 0, stream>>>(logits);

    gemm_pv_k<<<dim3(30, 4, 3), 256, 0, stream>>>(
        (const unsigned short*)logits, V, P, 1280, 7680, 3840, 512,
        1280L, 3840L * 512, b);
  }

  final_blend_k<<<dim3(113, 16), tb, 0, stream>>>(P, f_q, out);
}